// Round 20
// baseline (464.496 us; speedup 1.0000x reference)
//
#include <hip/hip_runtime.h>

#define TT 2048
#define BB 512
#define HH 64
#define HIST 64
#define HPAD 68   // R12-validated layout (0 conflicts measured)

typedef float f32x2 __attribute__((ext_vector_type(2)));
typedef float f32x4 __attribute__((ext_vector_type(4)));

#define FMA2(a, b, c) __builtin_elementwise_fma((a), (b), (c))
#define LO2(q) __builtin_shufflevector((q), (q), 0, 1)
#define HI2(q) __builtin_shufflevector((q), (q), 2, 3)

// DPP mov: value of v from lane (lane ^ mask); codes HW-validated (R15/R17/R19)
#define DPPM(v, ctrl) \
    __int_as_float(__builtin_amdgcn_update_dpp(0, __float_as_int(v), (ctrl), 0xF, 0xF, false))

// One wave per block. Lane L owns output row L. Hybrid exchange:
//  - own 16-block h values: XOR-DPP tree from live registers (ON chain, short)
//  - other 48 values: 12 ds_read_b128 from the ring written LAST step -> they
//    issue at step top and their latency hides under tanh+tree (OFF chain).
// No reduce-scatter, no permlane, no barrier.
__global__ __launch_bounds__(64, 1) void rnn_fused(
    const float* __restrict__ x,     // [T][B]
    const float* __restrict__ h0,    // [B][H]
    const float* __restrict__ Wih,   // [H]
    const float* __restrict__ Whh,   // [H][H]
    const float* __restrict__ bih,   // [H]
    const float* __restrict__ bhh,   // [H]
    const float* __restrict__ Wlin,  // [H]
    const float* __restrict__ blin,  // [1]
    float* __restrict__ y,           // [T][B]
    float* __restrict__ hN)          // [B][H]
{
    __shared__ float wsh[HH * HH];                    // W_hh staging
    __shared__ float xsh[TT + 4];                     // x column (+pad)
    __shared__ __align__(16) float hist[HIST][HPAD];  // h ring
    __shared__ __align__(16) float wlin_sh[HH];

    const int b  = blockIdx.x;    // batch column
    const int L  = threadIdx.x;   // hidden index / lane
    const int rb = L & 15;        // in-row index
    const int R  = L >> 4;        // 16-lane DPP row / block index

    // ---- Prologue (single wave, in-order DS pipe: no barriers) ----
    for (int i = L; i < HH * HH; i += 64) wsh[i] = Whh[i];
    for (int i = L; i < TT; i += 64)      xsh[i] = x[(size_t)i * BB + b];
    if (L < 4) xsh[TT + L] = 0.f;
    wlin_sh[L] = Wlin[L];

    const float KSC = 2.885390081777927f;  // 2/ln2 pre-scale (tanh via exp2)

    // DPP-part weights: wd[m] pairs with r[m] = h_{16R + (rb^m)}
    float wd[16];
#pragma unroll
    for (int m = 0; m < 16; ++m)
        wd[m] = wsh[L * HH + 16 * R + (rb ^ m)] * KSC;

    // LDS-part weights for the other 3 blocks (k-order, pk-paired)
    const int g1 = (R + 1) & 3, g2 = (R + 2) & 3, g3 = (R + 3) & 3;
    f32x2 wA[8], wB[8], wC[8];
#pragma unroll
    for (int j = 0; j < 8; ++j) {
        wA[j] = f32x2{wsh[L * HH + 16 * g1 + 2 * j], wsh[L * HH + 16 * g1 + 2 * j + 1]} * KSC;
        wB[j] = f32x2{wsh[L * HH + 16 * g2 + 2 * j], wsh[L * HH + 16 * g2 + 2 * j + 1]} * KSC;
        wC[j] = f32x2{wsh[L * HH + 16 * g3 + 2 * j], wsh[L * HH + 16 * g3 + 2 * j + 1]} * KSC;
    }
    const float wihs  = Wih[L] * KSC;
    const float biass = (bih[L] + bhh[L]) * KSC;
    const float bl    = blin[0];
    const int off1 = 16 * g1, off2 = 16 * g2, off3 = 16 * g3;

    hist[HIST - 1][L] = h0[(size_t)b * HH + L];  // slot 63 = h_0
    float hval = h0[(size_t)b * HH + L];
    float xw   = fmaf(xsh[0], wihs, biass);

    // ---- Recurrence ----
#pragma unroll 1
    for (int tc = 0; tc < TT; tc += HIST) {
#pragma unroll 2
        for (int ti = 0; ti < HIST; ++ti) {
            const int t  = tc + ti;
            const int rs = (ti + HIST - 1) & (HIST - 1);  // slot of h_{t-1}

            // EARLY: issue the 12 off-chain reads (other 3 blocks of h_{t-1})
            const f32x4* ha = reinterpret_cast<const f32x4*>(&hist[rs][off1]);
            const f32x4* hb = reinterpret_cast<const f32x4*>(&hist[rs][off2]);
            const f32x4* hc = reinterpret_cast<const f32x4*>(&hist[rs][off3]);
            const f32x4 A0 = ha[0], A1 = ha[1], A2 = ha[2], A3 = ha[3];
            const f32x4 B0 = hb[0], B1 = hb[1], B2 = hb[2], B3 = hb[3];
            const f32x4 C0 = hc[0], C1 = hc[1], C2 = hc[2], C3 = hc[3];

            // ON-CHAIN: 15-mov XOR-DPP tree for my own block (R17-validated)
            const float r0  = hval;
            const float r1  = DPPM(hval, 0xB1);   // xor1
            const float r2  = DPPM(hval, 0x4E);   // xor2
            const float r3  = DPPM(r2,   0xB1);   // xor3
            const float r7  = DPPM(hval, 0x141);  // xor7 (row_half_mirror)
            const float r6  = DPPM(r7,   0xB1);
            const float r5  = DPPM(r7,   0x4E);
            const float r4  = DPPM(r5,   0xB1);
            const float r15 = DPPM(hval, 0x140);  // xor15 (row_mirror)
            const float r14 = DPPM(r15,  0xB1);
            const float r13 = DPPM(r15,  0x4E);
            const float r12 = DPPM(r13,  0xB1);
            const float r8  = DPPM(r15,  0x141);  // xor8
            const float r9  = DPPM(r8,   0xB1);
            const float r10 = DPPM(r8,   0x4E);
            const float r11 = DPPM(r10,  0xB1);

            // DPP part: 16 scalar fma in 4 chains (4 deep)
            float d0 = 0.f, d1 = 0.f, d2 = 0.f, d3 = 0.f;
            d0 = fmaf(r0,  wd[0],  d0); d1 = fmaf(r1,  wd[1],  d1);
            d2 = fmaf(r2,  wd[2],  d2); d3 = fmaf(r3,  wd[3],  d3);
            d0 = fmaf(r4,  wd[4],  d0); d1 = fmaf(r5,  wd[5],  d1);
            d2 = fmaf(r6,  wd[6],  d2); d3 = fmaf(r7,  wd[7],  d3);
            d0 = fmaf(r8,  wd[8],  d0); d1 = fmaf(r9,  wd[9],  d1);
            d2 = fmaf(r10, wd[10], d2); d3 = fmaf(r11, wd[11], d3);
            d0 = fmaf(r12, wd[12], d0); d1 = fmaf(r13, wd[13], d1);
            d2 = fmaf(r14, wd[14], d2); d3 = fmaf(r15, wd[15], d3);

            // LDS part: 24 pk_fma in 6 chains (4 deep); xw folded in
            f32x2 aA = {xw, 0.f}, aA2 = {0.f, 0.f};
            f32x2 aB = {0.f, 0.f}, aB2 = {0.f, 0.f};
            f32x2 aC = {0.f, 0.f}, aC2 = {0.f, 0.f};
            aA = FMA2(LO2(A0), wA[0], aA); aA2 = FMA2(HI2(A0), wA[1], aA2);
            aA = FMA2(LO2(A1), wA[2], aA); aA2 = FMA2(HI2(A1), wA[3], aA2);
            aA = FMA2(LO2(A2), wA[4], aA); aA2 = FMA2(HI2(A2), wA[5], aA2);
            aA = FMA2(LO2(A3), wA[6], aA); aA2 = FMA2(HI2(A3), wA[7], aA2);
            aB = FMA2(LO2(B0), wB[0], aB); aB2 = FMA2(HI2(B0), wB[1], aB2);
            aB = FMA2(LO2(B1), wB[2], aB); aB2 = FMA2(HI2(B1), wB[3], aB2);
            aB = FMA2(LO2(B2), wB[4], aB); aB2 = FMA2(HI2(B2), wB[5], aB2);
            aB = FMA2(LO2(B3), wB[6], aB); aB2 = FMA2(HI2(B3), wB[7], aB2);
            aC = FMA2(LO2(C0), wC[0], aC); aC2 = FMA2(HI2(C0), wC[1], aC2);
            aC = FMA2(LO2(C1), wC[2], aC); aC2 = FMA2(HI2(C1), wC[3], aC2);
            aC = FMA2(LO2(C2), wC[4], aC); aC2 = FMA2(HI2(C2), wC[5], aC2);
            aC = FMA2(LO2(C3), wC[6], aC); aC2 = FMA2(HI2(C3), wC[7], aC2);

            const f32x2 sv = ((aA + aA2) + (aB + aB2)) + (aC + aC2);
            const float acc = (sv[0] + sv[1]) + ((d0 + d1) + (d2 + d3));

            // tanh = 1 - 2/(2^{acc}+1)   (pre-scaled by 2/ln2)
            const float e2 = __builtin_amdgcn_exp2f(acc);
            const float rc = __builtin_amdgcn_rcpf(e2 + 1.0f);
            hval = fmaf(-2.0f, rc, 1.0f);

            // publish h_t (stride-1: 2 lanes/bank, free)
            hist[ti][L] = hval;

            // next-step x projection (off-chain)
            xw = fmaf(xsh[t + 1], wihs, biass);
        }

        // ---- bulk y: lane -> t = tc + lane (R12-validated, 0 conflicts) ----
        {
            const f32x4* rp = reinterpret_cast<const f32x4*>(&hist[L][0]);
            const f32x4* wl = reinterpret_cast<const f32x4*>(&wlin_sh[0]);
            f32x2 a2 = {0.f, 0.f};
#pragma unroll
            for (int i = 0; i < 16; ++i) {
                const f32x4 q  = rp[i];
                const f32x4 qw = wl[i];
                a2 = FMA2(LO2(q), LO2(qw), a2);
                a2 = FMA2(HI2(q), HI2(qw), a2);
            }
            y[(size_t)(tc + L) * BB + b] = a2[0] + a2[1] + bl;
        }
        // same wave: next chunk's ring writes are ordered after these reads
    }

    // ---- Epilogue ----
    hN[(size_t)b * HH + L] = hval;
}

extern "C" void kernel_launch(void* const* d_in, const int* in_sizes, int n_in,
                              void* d_out, int out_size, void* d_ws, size_t ws_size,
                              hipStream_t stream) {
    const float* x    = (const float*)d_in[0];
    const float* h0   = (const float*)d_in[1];
    const float* Wih  = (const float*)d_in[2];
    const float* Whh  = (const float*)d_in[3];
    const float* bih  = (const float*)d_in[4];
    const float* bhh  = (const float*)d_in[5];
    const float* Wlin = (const float*)d_in[6];
    const float* blin = (const float*)d_in[7];

    float* y  = (float*)d_out;            // [T*B]
    float* hN = (float*)d_out + TT * BB;  // [B*H]

    rnn_fused<<<dim3(BB), dim3(64), 0, stream>>>(x, h0, Wih, Whh, bih, bhh, Wlin, blin, y, hN);
}